// Round 10
// baseline (79.719 us; speedup 1.0000x reference)
//
#include <hip/hip_runtime.h>
#include <hip/hip_bf16.h>

// N=256, T=12, F=32, T_dim=8, D=64;  c-index: c = kk*768 + t*64 + d  (size 6144)
typedef unsigned short ushort_t;
typedef __bf16 bf16x8 __attribute__((ext_vector_type(8)));
typedef float f32x4 __attribute__((ext_vector_type(4)));
typedef ushort_t ushort8 __attribute__((ext_vector_type(8)));
typedef ushort_t ushort4v __attribute__((ext_vector_type(4)));

#define GLOAD16(gp, lp) \
    __builtin_amdgcn_global_load_lds((const __attribute__((address_space(1))) void*)(gp), \
                                     (__attribute__((address_space(3))) void*)(lp), 16, 0, 0)

__device__ __forceinline__ ushort_t bf16bits(float x) {
    __hip_bfloat16 h = __float2bfloat16(x);
    return *(ushort_t*)&h;
}
__device__ __forceinline__ float bf2f(ushort_t u) {
    unsigned v = (unsigned)u << 16;
    float f;
    __builtin_memcpy(&f, &v, 4);
    return f;
}

// ---------------------------------------------------------------- K1: QKV projection — streaming, one wave per (b, mat)
__global__ __launch_bounds__(256) void qkv_kernel(
    const float* __restrict__ x,
    const float* __restrict__ Wq, const float* __restrict__ Wk, const float* __restrict__ Wv,
    const float* __restrict__ bq, const float* __restrict__ bk, const float* __restrict__ bv,
    ushort_t* __restrict__ qhi, ushort_t* __restrict__ kbf, ushort_t* __restrict__ vbf)
{
    __shared__ float xs[4][12 * 36];       // per-wave x row, t-stride 36
    int tid = threadIdx.x;
    int wid = tid >> 6, l = tid & 63;
    int gid = blockIdx.x * 4 + wid;        // 0..6143, mat-major
    int mat = gid >> 11, b = gid & 2047;
    int j = b >> 3;

    const float* W    = (mat == 0) ? Wq : (mat == 1) ? Wk : Wv;
    const float* bias = (mat == 0) ? bq : (mat == 1) ? bk : bv;
    ushort_t*    out  = (mat == 0) ? qhi : (mat == 1) ? kbf : vbf;
    float scale = (mat == 0) ? 0.125f : 1.0f;

    {
        const float4* xsrc = (const float4*)(x + (size_t)j * 384);
        float4 g0 = xsrc[l];
        int flat0 = l * 4;
        float* dst0 = &xs[wid][(flat0 >> 5) * 36 + (flat0 & 31)];
        dst0[0] = g0.x; dst0[1] = g0.y; dst0[2] = g0.z; dst0[3] = g0.w;
        if (l < 32) {
            float4 g1 = xsrc[64 + l];
            int flat1 = 256 + l * 4;
            float* dst1 = &xs[wid][(flat1 >> 5) * 36 + (flat1 & 31)];
            dst1[0] = g1.x; dst1[1] = g1.y; dst1[2] = g1.z; dst1[3] = g1.w;
        }
    }
    __syncthreads();

    int dq = l & 15, tg = l >> 4;          // d-quad, t-group (t = tg*3 + i)
    const f32x4* w4 = (const f32x4*)(W + (size_t)b * 2048);
    f32x4 a0 = {0.f,0.f,0.f,0.f}, a1 = a0, a2 = a0;
    const float* xr = &xs[wid][tg * 3 * 36];
    #pragma unroll
    for (int f4 = 0; f4 < 8; ++f4) {
        f32x4 w0 = w4[(f4 * 4 + 0) * 16 + dq];
        f32x4 w1_ = w4[(f4 * 4 + 1) * 16 + dq];
        f32x4 w2_ = w4[(f4 * 4 + 2) * 16 + dq];
        f32x4 w3_ = w4[(f4 * 4 + 3) * 16 + dq];
        float4 xa = *(const float4*)&xr[0 * 36 + f4 * 4];
        float4 xb = *(const float4*)&xr[1 * 36 + f4 * 4];
        float4 xc = *(const float4*)&xr[2 * 36 + f4 * 4];
        a0 += w0 * xa.x + w1_ * xa.y + w2_ * xa.z + w3_ * xa.w;
        a1 += w0 * xb.x + w1_ * xb.y + w2_ * xb.z + w3_ * xb.w;
        a2 += w0 * xc.x + w1_ * xc.y + w2_ * xc.z + w3_ * xc.w;
    }

    f32x4 bv4 = *(const f32x4*)(bias + (size_t)b * 64 + dq * 4);
    size_t obase = (size_t)b * 768 + dq * 4;
    f32x4 r;
    ushort4v u;
    r = (a0 + bv4) * scale;
    u[0] = bf16bits(r[0]); u[1] = bf16bits(r[1]); u[2] = bf16bits(r[2]); u[3] = bf16bits(r[3]);
    *(ushort4v*)(out + obase + (size_t)(tg * 3 + 0) * 64) = u;
    r = (a1 + bv4) * scale;
    u[0] = bf16bits(r[0]); u[1] = bf16bits(r[1]); u[2] = bf16bits(r[2]); u[3] = bf16bits(r[3]);
    *(ushort4v*)(out + obase + (size_t)(tg * 3 + 1) * 64) = u;
    r = (a2 + bv4) * scale;
    u[0] = bf16bits(r[0]); u[1] = bf16bits(r[1]); u[2] = bf16bits(r[2]); u[3] = bf16bits(r[3]);
    *(ushort4v*)(out + obase + (size_t)(tg * 3 + 2) * 64) = u;
}

// ---------------------------------------------------------------- K2: G build (0..2047) + vt (2048..2431) + w3t (2432..2447) + w4t (2448)
__global__ __launch_bounds__(256) void gbuild_kernel(
    const ushort_t* __restrict__ kbf, const float* __restrict__ w1,
    const ushort_t* __restrict__ vbf, const float* __restrict__ w3, const float* __restrict__ w4,
    ushort_t* __restrict__ ghi, ushort_t* __restrict__ vt,
    float* __restrict__ w3t, float* __restrict__ w4t)
{
    __shared__ alignas(16) char sbuf[8448];
    int bx = blockIdx.x, tid = threadIdx.x;

    if (bx < 2048) {
        float* w1s = (float*)sbuf;            // [m][144]
        float* ks  = (float*)sbuf + 1152;     // k row fp32 [t][d]
        int b = bx, j = b >> 3, kk = b & 7;

        #pragma unroll
        for (int r = 0; r < 2; ++r) {
            int c = r * 256 + tid;
            if (c < 288)
                GLOAD16(w1 + (c / 36) * 1152 + kk * 144 + (c % 36) * 4, &w1s[c * 4]);
        }
        if (tid < 96) {
            ushort8 uu = *(const ushort8*)(kbf + (size_t)b * 768 + tid * 8);
            float4 f0, f1;
            f0.x = bf2f(uu[0]); f0.y = bf2f(uu[1]); f0.z = bf2f(uu[2]); f0.w = bf2f(uu[3]);
            f1.x = bf2f(uu[4]); f1.y = bf2f(uu[5]); f1.z = bf2f(uu[6]); f1.w = bf2f(uu[7]);
            ((float4*)ks)[tid * 2]     = f0;
            ((float4*)ks)[tid * 2 + 1] = f1;
        }
        __syncthreads();

        #pragma unroll
        for (int r = 0; r < 3; ++r) {
            int e = r * 256 + tid;               // (m, t, d8)
            int m = e / 96, rem = e - m * 96;
            int t = rem >> 3, d8 = rem & 7;
            const float* w1p = w1s + m * 144 + t * 12;
            float acc[8] = {0.f,0.f,0.f,0.f,0.f,0.f,0.f,0.f};
            #pragma unroll
            for (int s = 0; s < 12; ++s) {
                float wv = w1p[s];
                const float4* kp = (const float4*)(ks + s * 64 + d8 * 8);
                float4 k0 = kp[0], k1 = kp[1];
                acc[0] += wv * k0.x; acc[1] += wv * k0.y;
                acc[2] += wv * k0.z; acc[3] += wv * k0.w;
                acc[4] += wv * k1.x; acc[5] += wv * k1.y;
                acc[6] += wv * k1.z; acc[7] += wv * k1.w;
            }
            ushort8 u;
            #pragma unroll
            for (int dd = 0; dd < 8; ++dd) u[dd] = bf16bits(acc[dd]);
            *(ushort8*)(ghi + ((size_t)j * 8 + m) * 6144 + kk * 768 + t * 64 + d8 * 8) = u;
        }
        return;
    }

    if (bx < 2432) {
        ushort_t (*ts)[264] = (ushort_t(*)[264])sbuf;
        int c0 = (bx - 2048) * 16;
        int cc = tid & 15, jg = tid >> 4;
        #pragma unroll 4
        for (int jj = 0; jj < 16; ++jj) {
            int jx = jg * 16 + jj;
            ts[cc][jx] = vbf[(size_t)jx * 6144 + c0 + cc];
        }
        __syncthreads();
        #pragma unroll
        for (int c = 0; c < 16; ++c)
            vt[(size_t)(c0 + c) * 256 + tid] = ts[c][tid];
        return;
    }
    if (bx < 2448) {
        int wb = bx - 2432;
        #pragma unroll
        for (int r = 0; r < 8; ++r) {
            int e = wb * 2048 + r * 256 + tid;
            int dout = e >> 9, c3 = e & 511;
            int cb = ((c3 & 7) << 6) | (c3 >> 3);
            w3t[cb * 64 + dout] = w3[e];
        }
        return;
    }
    #pragma unroll
    for (int r = 0; r < 8; ++r) {
        int e = r * 256 + tid; int f = e >> 6, dd = e & 63;
        w4t[dd * 32 + f] = w4[e];
    }
}

// ---------------------------------------------------------------- K3: H GEMM (swapped operands: A=ghi(n), B=qhi(i))
// acc rows = n (consecutive) -> 8B stores. block 128n x 128i, BK=64, 6 steps, nz=16, XCD z-major
__global__ __launch_bounds__(256, 2) void hgemm_kernel(
    const ushort_t* __restrict__ qhi, const ushort_t* __restrict__ ghi,
    ushort_t* __restrict__ hpart)
{
    __shared__ ushort_t As[2][128 * 64];   // ghi rows
    __shared__ ushort_t Bs[2][128 * 64];   // qhi rows

    int tid = threadIdx.x;
    int bid = blockIdx.x;                 // 0..511
    int lane = tid & 63, wid = tid >> 6;
    int wr = wid >> 1, wc = wid & 1;
    int xcd = bid & 7, kq = bid >> 3;
    int z = xcd + 8 * (kq >> 5);
    int rem = kq & 31;
    int n0 = (rem & 15) * 128, i0 = (rem >> 4) * 128;
    int kbase = z * 384;
    ushort_t* Hout = hpart + (size_t)z * 524288;

    f32x4 acc[4][4] = {};

    #define STAGE(buf, koff)                                                                 \
    {                                                                                        \
        _Pragma("unroll")                                                                    \
        for (int r = 0; r < 4; ++r) {                                                        \
            int c = r * 256 + tid; int row = c >> 3, slot = c & 7;                           \
            int so = (koff) + ((slot ^ (row & 7)) * 8);                                      \
            GLOAD16(ghi + (size_t)(n0 + row) * 6144 + so, &As[buf][c * 8]);                  \
            GLOAD16(qhi + (size_t)(i0 + row) * 6144 + so, &Bs[buf][c * 8]);                  \
        }                                                                                    \
    }

    STAGE(0, kbase);
    int cur = 0;
    for (int s = 0; s < 6; ++s) {
        __syncthreads();
        if (s + 1 < 6) STAGE(cur ^ 1, kbase + (s + 1) * 64);
        #pragma unroll
        for (int kh = 0; kh < 2; ++kh) {
            bf16x8 a[4], b[4];
            #pragma unroll
            for (int mi = 0; mi < 4; ++mi) {
                int row = wr * 64 + mi * 16 + (lane & 15);
                int slot = (kh * 4 + (lane >> 4)) ^ (row & 7);
                a[mi] = *(const bf16x8*)&As[cur][row * 64 + slot * 8];
            }
            #pragma unroll
            for (int ni = 0; ni < 4; ++ni) {
                int row = wc * 64 + ni * 16 + (lane & 15);
                int slot = (kh * 4 + (lane >> 4)) ^ (row & 7);
                b[ni] = *(const bf16x8*)&Bs[cur][row * 64 + slot * 8];
            }
            #pragma unroll
            for (int mi = 0; mi < 4; ++mi)
                #pragma unroll
                for (int ni = 0; ni < 4; ++ni)
                    acc[mi][ni] = __builtin_amdgcn_mfma_f32_16x16x32_bf16(a[mi], b[ni], acc[mi][ni], 0, 0, 0);
        }
        cur ^= 1;
    }
    #undef STAGE

    // acc[mi][ni]: rows = n (4 consecutive at r4), col = i
    int r4 = (lane >> 4) * 4, cn = lane & 15;
    #pragma unroll
    for (int mi = 0; mi < 4; ++mi)
        #pragma unroll
        for (int ni = 0; ni < 4; ++ni) {
            int i = i0 + wc * 64 + ni * 16 + cn;
            int nb = n0 + wr * 64 + mi * 16 + r4;
            ushort4v u;
            #pragma unroll
            for (int r = 0; r < 4; ++r) u[r] = bf16bits(acc[mi][ni][r]);
            *(ushort4v*)(Hout + (size_t)i * 2048 + nb) = u;
        }
}

// ---------------------------------------------------------------- K4: z-reduce + score + softmax (+ bf16 att)
__global__ __launch_bounds__(256) void score_softmax_kernel(
    const ushort_t* __restrict__ hpart, const float* __restrict__ b1g,
    const float* __restrict__ w2g, const float* __restrict__ b2g,
    float* __restrict__ att, ushort_t* __restrict__ attbf)
{
    int i = blockIdx.x, j = threadIdx.x;
    float hm[8];
    #pragma unroll
    for (int m = 0; m < 8; ++m) hm[m] = b1g[m];
    #pragma unroll 4
    for (int z = 0; z < 16; ++z) {
        ushort8 u = *(const ushort8*)(hpart + (size_t)z * 524288 + (size_t)i * 2048 + j * 8);
        #pragma unroll
        for (int m = 0; m < 8; ++m) hm[m] += bf2f(u[m]);
    }
    float sv = b2g[0];
    #pragma unroll
    for (int m = 0; m < 8; ++m) sv += fmaxf(hm[m], 0.f) * w2g[m];

    __shared__ float wred[4], wred2[4];
    float mx = sv;
    #pragma unroll
    for (int off = 32; off > 0; off >>= 1) mx = fmaxf(mx, __shfl_down(mx, off, 64));
    if ((j & 63) == 0) wred[j >> 6] = mx;
    __syncthreads();
    mx = fmaxf(fmaxf(wred[0], wred[1]), fmaxf(wred[2], wred[3]));

    float e = expf(sv - mx);
    float sum = e;
    #pragma unroll
    for (int off = 32; off > 0; off >>= 1) sum += __shfl_down(sum, off, 64);
    if ((j & 63) == 0) wred2[j >> 6] = sum;
    __syncthreads();
    sum = wred2[0] + wred2[1] + wred2[2] + wred2[3];

    float pv = e / sum;
    att[(size_t)i * 256 + j] = pv;
    attbf[(size_t)i * 256 + j] = bf16bits(pv);
}

// ---------------------------------------------------------------- K5: b = att @ v (swapped: A=vt(c), B=attbf(i)) -> float4 stores
__global__ __launch_bounds__(256) void av_kernel(
    const ushort_t* __restrict__ attbf, const ushort_t* __restrict__ vt,
    float* __restrict__ bmat)
{
    __shared__ ushort_t As[2][128 * 64];   // vt rows (c)
    __shared__ ushort_t Bs[2][128 * 64];   // attbf rows (i)

    int tid = threadIdx.x, lane = tid & 63, wid = tid >> 6;
    int wr = wid >> 1, wc = wid & 1;
    int c0 = blockIdx.x * 128, i0 = blockIdx.y * 128;

    f32x4 acc[4][4] = {};

    #define STAGEAV(buf, koff)                                                              \
    {                                                                                       \
        _Pragma("unroll")                                                                   \
        for (int r = 0; r < 4; ++r) {                                                       \
            int c = r * 256 + tid; int row = c >> 3, slot = c & 7;                          \
            int so = (koff) + ((slot ^ (row & 7)) * 8);                                     \
            GLOAD16(vt + (size_t)(c0 + row) * 256 + so, &As[buf][c * 8]);                   \
            GLOAD16(attbf + (size_t)(i0 + row) * 256 + so, &Bs[buf][c * 8]);                \
        }                                                                                   \
    }

    int cur = 0;
    STAGEAV(0, 0);
    for (int s = 0; s < 4; ++s) {
        __syncthreads();
        if (s < 3) STAGEAV(cur ^ 1, (s + 1) * 64);
        #pragma unroll
        for (int kh = 0; kh < 2; ++kh) {
            bf16x8 a[4], b[4];
            #pragma unroll
            for (int mi = 0; mi < 4; ++mi) {
                int row = wr * 64 + mi * 16 + (lane & 15);
                int slot = (kh * 4 + (lane >> 4)) ^ (row & 7);
                a[mi] = *(const bf16x8*)&As[cur][row * 64 + slot * 8];
            }
            #pragma unroll
            for (int ni = 0; ni < 4; ++ni) {
                int row = wc * 64 + ni * 16 + (lane & 15);
                int slot = (kh * 4 + (lane >> 4)) ^ (row & 7);
                b[ni] = *(const bf16x8*)&Bs[cur][row * 64 + slot * 8];
            }
            #pragma unroll
            for (int mi = 0; mi < 4; ++mi)
                #pragma unroll
                for (int ni = 0; ni < 4; ++ni)
                    acc[mi][ni] = __builtin_amdgcn_mfma_f32_16x16x32_bf16(a[mi], b[ni], acc[mi][ni], 0, 0, 0);
        }
        cur ^= 1;
    }
    #undef STAGEAV

    // acc[mi][ni]: rows = c (4 consecutive at r4), col = i
    int r4 = (lane >> 4) * 4, cn = lane & 15;
    #pragma unroll
    for (int mi = 0; mi < 4; ++mi)
        #pragma unroll
        for (int ni = 0; ni < 4; ++ni) {
            int i = i0 + wc * 64 + ni * 16 + cn;
            int c = c0 + wr * 64 + mi * 16 + r4;
            int kk = c / 768, rem = c - kk * 768;
            int t = rem >> 6, d = rem & 63;
            float4 val;
            val.x = acc[mi][ni][0]; val.y = acc[mi][ni][1];
            val.z = acc[mi][ni][2]; val.w = acc[mi][ni][3];
            *(float4*)(bmat + ((size_t)i * 12 + t) * 512 + kk * 64 + d) = val;
        }
}

// ---------------------------------------------------------------- K6: y = relu(b@w3T+b3)@w4T+b4
__global__ __launch_bounds__(256) void out_kernel(
    const float* __restrict__ bmat, const float* __restrict__ w3t, const float* __restrict__ b3,
    const float* __restrict__ w4t, const float* __restrict__ b4, float* __restrict__ yout)
{
    int rb = blockIdx.x * 16;     // rows (i*12+t)
    int tid = threadIdx.x;
    __shared__ float rows[16 * 512];
    __shared__ float y1s[16 * 64];
    const float4* src = (const float4*)(bmat + (size_t)rb * 512);
    #pragma unroll
    for (int r = 0; r < 8; ++r) ((float4*)rows)[tid + r * 256] = src[tid + r * 256];
    __syncthreads();

    int dout = tid & 63, rg = tid >> 6;
    float acc[4];
    float b3v = b3[dout];
    #pragma unroll
    for (int jj = 0; jj < 4; ++jj) acc[jj] = b3v;
    for (int c4 = 0; c4 < 128; ++c4) {
        float w0 = w3t[(c4 * 4 + 0) * 64 + dout];
        float w1v = w3t[(c4 * 4 + 1) * 64 + dout];
        float w2v = w3t[(c4 * 4 + 2) * 64 + dout];
        float w3v = w3t[(c4 * 4 + 3) * 64 + dout];
        #pragma unroll
        for (int jj = 0; jj < 4; ++jj) {
            float4 rv = *(const float4*)&rows[(rg * 4 + jj) * 512 + c4 * 4];
            acc[jj] += rv.x * w0 + rv.y * w1v + rv.z * w2v + rv.w * w3v;
        }
    }
    #pragma unroll
    for (int jj = 0; jj < 4; ++jj) y1s[(rg * 4 + jj) * 64 + dout] = fmaxf(acc[jj], 0.f);
    __syncthreads();

    int f = tid & 31, rh = tid >> 5;
    #pragma unroll
    for (int rr = 0; rr < 2; ++rr) {
        int r = rh * 2 + rr;
        float a2 = b4[f];
        #pragma unroll
        for (int dd = 0; dd < 64; ++dd) a2 += y1s[r * 64 + dd] * w4t[dd * 32 + f];
        yout[(size_t)(rb + r) * 32 + f] = a2;
    }
}

// ---------------------------------------------------------------- launch
extern "C" void kernel_launch(void* const* d_in, const int* in_sizes, int n_in,
                              void* d_out, int out_size, void* d_ws, size_t ws_size,
                              hipStream_t stream) {
    (void)in_sizes; (void)n_in; (void)out_size; (void)ws_size;
    const float* x  = (const float*)d_in[0];
    const float* Wq = (const float*)d_in[1];
    const float* Wk = (const float*)d_in[2];
    const float* Wv = (const float*)d_in[3];
    const float* bq = (const float*)d_in[4];
    const float* bk = (const float*)d_in[5];
    const float* bv = (const float*)d_in[6];
    const float* w1 = (const float*)d_in[7];
    const float* b1 = (const float*)d_in[8];
    const float* w2 = (const float*)d_in[9];
    const float* b2 = (const float*)d_in[10];
    const float* w3 = (const float*)d_in[11];
    const float* b3 = (const float*)d_in[12];
    const float* w4 = (const float*)d_in[13];
    const float* b4 = (const float*)d_in[14];

    float* ws = (float*)d_ws;
    ushort_t* hpart = (ushort_t*)ws;                     // 16z x 524288 ushorts = [0, 4194304) float-slots
    size_t    off   = 4194304;
    ushort_t* qhi   = (ushort_t*)(ws + off);             // 1,572,864 ushorts
    ushort_t* ghi   = (ushort_t*)(ws + off + 786432);    // 12,582,912 ushorts
    ushort_t* vbf   = (ushort_t*)(ws + off + 7077888);   // 1,572,864 ushorts
    ushort_t* vt    = (ushort_t*)(ws + off + 7864320);   // 1,572,864 ushorts
    ushort_t* attbf = (ushort_t*)(ws + off + 8650752);   // 65,536 ushorts
    float*    w3t   = ws + off + 8683520;                // 32,768
    float*    w4t   = ws + off + 8716288;                // 2,048
    ushort_t* kbf   = (ushort_t*)(ws + off + 8718336);   // 1,572,864 ushorts
    float*    bmat  = (float*)ghi;                       // reuse (ghi dead after hgemm)

    float* yout = (float*)d_out;              // 98304
    float* att  = (float*)d_out + 98304;      // 65536

    qkv_kernel<<<1536, 256, 0, stream>>>(x, Wq, Wk, Wv, bq, bk, bv, qhi, kbf, vbf);
    gbuild_kernel<<<2449, 256, 0, stream>>>(kbf, w1, vbf, w3, w4, ghi, vt, w3t, w4t);
    hgemm_kernel<<<512, 256, 0, stream>>>(qhi, ghi, hpart);
    score_softmax_kernel<<<256, 256, 0, stream>>>(hpart, b1, w2, b2, att, attbf);
    av_kernel<<<dim3(48, 2), 256, 0, stream>>>(attbf, vt, bmat);
    out_kernel<<<192, 256, 0, stream>>>(bmat, w3t, b3, w4t, b4, yout);
}

// Round 11
// 75.416 us; speedup vs baseline: 1.0571x; 1.0571x over previous
//
#include <hip/hip_runtime.h>
#include <hip/hip_bf16.h>

// N=256, T=12, F=32, T_dim=8, D=64;  c-index: c = kk*768 + t*64 + d  (size 6144)
typedef unsigned short ushort_t;
typedef __bf16 bf16x8 __attribute__((ext_vector_type(8)));
typedef float f32x4 __attribute__((ext_vector_type(4)));
typedef ushort_t ushort8 __attribute__((ext_vector_type(8)));
typedef ushort_t ushort4v __attribute__((ext_vector_type(4)));

#define GLOAD16(gp, lp) \
    __builtin_amdgcn_global_load_lds((const __attribute__((address_space(1))) void*)(gp), \
                                     (__attribute__((address_space(3))) void*)(lp), 16, 0, 0)

__device__ __forceinline__ ushort_t bf16bits(float x) {
    __hip_bfloat16 h = __float2bfloat16(x);
    return *(ushort_t*)&h;
}
__device__ __forceinline__ float bf2f(ushort_t u) {
    unsigned v = (unsigned)u << 16;
    float f;
    __builtin_memcpy(&f, &v, 4);
    return f;
}

// ---------------------------------------------------------------- K1: QKV projection — streaming, one wave per (b, mat)
__global__ __launch_bounds__(256) void qkv_kernel(
    const float* __restrict__ x,
    const float* __restrict__ Wq, const float* __restrict__ Wk, const float* __restrict__ Wv,
    const float* __restrict__ bq, const float* __restrict__ bk, const float* __restrict__ bv,
    ushort_t* __restrict__ qhi, ushort_t* __restrict__ kbf, ushort_t* __restrict__ vbf)
{
    __shared__ float xs[4][12 * 36];       // per-wave x row, t-stride 36
    int tid = threadIdx.x;
    int wid = tid >> 6, l = tid & 63;
    int gid = blockIdx.x * 4 + wid;        // 0..6143, mat-major
    int mat = gid >> 11, b = gid & 2047;
    int j = b >> 3;

    const float* W    = (mat == 0) ? Wq : (mat == 1) ? Wk : Wv;
    const float* bias = (mat == 0) ? bq : (mat == 1) ? bk : bv;
    ushort_t*    out  = (mat == 0) ? qhi : (mat == 1) ? kbf : vbf;
    float scale = (mat == 0) ? 0.125f : 1.0f;

    {
        const float4* xsrc = (const float4*)(x + (size_t)j * 384);
        float4 g0 = xsrc[l];
        int flat0 = l * 4;
        float* dst0 = &xs[wid][(flat0 >> 5) * 36 + (flat0 & 31)];
        dst0[0] = g0.x; dst0[1] = g0.y; dst0[2] = g0.z; dst0[3] = g0.w;
        if (l < 32) {
            float4 g1 = xsrc[64 + l];
            int flat1 = 256 + l * 4;
            float* dst1 = &xs[wid][(flat1 >> 5) * 36 + (flat1 & 31)];
            dst1[0] = g1.x; dst1[1] = g1.y; dst1[2] = g1.z; dst1[3] = g1.w;
        }
    }
    __syncthreads();

    int dq = l & 15, tg = l >> 4;          // d-quad, t-group (t = tg*3 + i)
    const f32x4* w4 = (const f32x4*)(W + (size_t)b * 2048);
    f32x4 a0 = {0.f,0.f,0.f,0.f}, a1 = a0, a2 = a0;
    const float* xr = &xs[wid][tg * 3 * 36];
    #pragma unroll
    for (int f4 = 0; f4 < 8; ++f4) {
        f32x4 w0 = w4[(f4 * 4 + 0) * 16 + dq];
        f32x4 w1_ = w4[(f4 * 4 + 1) * 16 + dq];
        f32x4 w2_ = w4[(f4 * 4 + 2) * 16 + dq];
        f32x4 w3_ = w4[(f4 * 4 + 3) * 16 + dq];
        float4 xa = *(const float4*)&xr[0 * 36 + f4 * 4];
        float4 xb = *(const float4*)&xr[1 * 36 + f4 * 4];
        float4 xc = *(const float4*)&xr[2 * 36 + f4 * 4];
        a0 += w0 * xa.x + w1_ * xa.y + w2_ * xa.z + w3_ * xa.w;
        a1 += w0 * xb.x + w1_ * xb.y + w2_ * xb.z + w3_ * xb.w;
        a2 += w0 * xc.x + w1_ * xc.y + w2_ * xc.z + w3_ * xc.w;
    }

    f32x4 bv4 = *(const f32x4*)(bias + (size_t)b * 64 + dq * 4);
    size_t obase = (size_t)b * 768 + dq * 4;
    f32x4 r;
    ushort4v u;
    r = (a0 + bv4) * scale;
    u[0] = bf16bits(r[0]); u[1] = bf16bits(r[1]); u[2] = bf16bits(r[2]); u[3] = bf16bits(r[3]);
    *(ushort4v*)(out + obase + (size_t)(tg * 3 + 0) * 64) = u;
    r = (a1 + bv4) * scale;
    u[0] = bf16bits(r[0]); u[1] = bf16bits(r[1]); u[2] = bf16bits(r[2]); u[3] = bf16bits(r[3]);
    *(ushort4v*)(out + obase + (size_t)(tg * 3 + 1) * 64) = u;
    r = (a2 + bv4) * scale;
    u[0] = bf16bits(r[0]); u[1] = bf16bits(r[1]); u[2] = bf16bits(r[2]); u[3] = bf16bits(r[3]);
    *(ushort4v*)(out + obase + (size_t)(tg * 3 + 2) * 64) = u;
}

// ---------------------------------------------------------------- K2: G build (0..2047) + vt (2048..2431) + w3t (2432..2447) + w4t (2448)
__global__ __launch_bounds__(256) void gbuild_kernel(
    const ushort_t* __restrict__ kbf, const float* __restrict__ w1,
    const ushort_t* __restrict__ vbf, const float* __restrict__ w3, const float* __restrict__ w4,
    ushort_t* __restrict__ ghi, ushort_t* __restrict__ vt,
    float* __restrict__ w3t, float* __restrict__ w4t)
{
    __shared__ alignas(16) char sbuf[8448];
    int bx = blockIdx.x, tid = threadIdx.x;

    if (bx < 2048) {
        float* w1s = (float*)sbuf;            // [m][144]
        float* ks  = (float*)sbuf + 1152;     // k row fp32 [t][d]
        int b = bx, j = b >> 3, kk = b & 7;

        #pragma unroll
        for (int r = 0; r < 2; ++r) {
            int c = r * 256 + tid;
            if (c < 288)
                GLOAD16(w1 + (c / 36) * 1152 + kk * 144 + (c % 36) * 4, &w1s[c * 4]);
        }
        if (tid < 96) {
            ushort8 uu = *(const ushort8*)(kbf + (size_t)b * 768 + tid * 8);
            float4 f0, f1;
            f0.x = bf2f(uu[0]); f0.y = bf2f(uu[1]); f0.z = bf2f(uu[2]); f0.w = bf2f(uu[3]);
            f1.x = bf2f(uu[4]); f1.y = bf2f(uu[5]); f1.z = bf2f(uu[6]); f1.w = bf2f(uu[7]);
            ((float4*)ks)[tid * 2]     = f0;
            ((float4*)ks)[tid * 2 + 1] = f1;
        }
        __syncthreads();

        #pragma unroll
        for (int r = 0; r < 3; ++r) {
            int e = r * 256 + tid;               // (m, t, d8)
            int m = e / 96, rem = e - m * 96;
            int t = rem >> 3, d8 = rem & 7;
            const float* w1p = w1s + m * 144 + t * 12;
            float acc[8] = {0.f,0.f,0.f,0.f,0.f,0.f,0.f,0.f};
            #pragma unroll
            for (int s = 0; s < 12; ++s) {
                float wv = w1p[s];
                const float4* kp = (const float4*)(ks + s * 64 + d8 * 8);
                float4 k0 = kp[0], k1 = kp[1];
                acc[0] += wv * k0.x; acc[1] += wv * k0.y;
                acc[2] += wv * k0.z; acc[3] += wv * k0.w;
                acc[4] += wv * k1.x; acc[5] += wv * k1.y;
                acc[6] += wv * k1.z; acc[7] += wv * k1.w;
            }
            ushort8 u;
            #pragma unroll
            for (int dd = 0; dd < 8; ++dd) u[dd] = bf16bits(acc[dd]);
            *(ushort8*)(ghi + ((size_t)j * 8 + m) * 6144 + kk * 768 + t * 64 + d8 * 8) = u;
        }
        return;
    }

    if (bx < 2432) {
        ushort_t (*ts)[264] = (ushort_t(*)[264])sbuf;
        int c0 = (bx - 2048) * 16;
        int cc = tid & 15, jg = tid >> 4;
        #pragma unroll 4
        for (int jj = 0; jj < 16; ++jj) {
            int jx = jg * 16 + jj;
            ts[cc][jx] = vbf[(size_t)jx * 6144 + c0 + cc];
        }
        __syncthreads();
        #pragma unroll
        for (int c = 0; c < 16; ++c)
            vt[(size_t)(c0 + c) * 256 + tid] = ts[c][tid];
        return;
    }
    if (bx < 2448) {
        int wb = bx - 2432;
        #pragma unroll
        for (int r = 0; r < 8; ++r) {
            int e = wb * 2048 + r * 256 + tid;
            int dout = e >> 9, c3 = e & 511;
            int cb = ((c3 & 7) << 6) | (c3 >> 3);
            w3t[cb * 64 + dout] = w3[e];
        }
        return;
    }
    #pragma unroll
    for (int r = 0; r < 8; ++r) {
        int e = r * 256 + tid; int f = e >> 6, dd = e & 63;
        w4t[dd * 32 + f] = w4[e];
    }
}

// ---------------------------------------------------------------- K3: H GEMM (A=ghi(n), B=qhi(i)), BK=64, nz=16, XCD z-major
__global__ __launch_bounds__(256, 2) void hgemm_kernel(
    const ushort_t* __restrict__ qhi, const ushort_t* __restrict__ ghi,
    ushort_t* __restrict__ hpart)
{
    __shared__ ushort_t As[2][128 * 64];   // ghi rows
    __shared__ ushort_t Bs[2][128 * 64];   // qhi rows

    int tid = threadIdx.x;
    int bid = blockIdx.x;                 // 0..511
    int lane = tid & 63, wid = tid >> 6;
    int wr = wid >> 1, wc = wid & 1;
    int xcd = bid & 7, kq = bid >> 3;
    int z = xcd + 8 * (kq >> 5);
    int rem = kq & 31;
    int n0 = (rem & 15) * 128, i0 = (rem >> 4) * 128;
    int kbase = z * 384;
    ushort_t* Hout = hpart + (size_t)z * 524288;

    f32x4 acc[4][4] = {};

    #define STAGE(buf, koff)                                                                 \
    {                                                                                        \
        _Pragma("unroll")                                                                    \
        for (int r = 0; r < 4; ++r) {                                                        \
            int c = r * 256 + tid; int row = c >> 3, slot = c & 7;                           \
            int so = (koff) + ((slot ^ (row & 7)) * 8);                                      \
            GLOAD16(ghi + (size_t)(n0 + row) * 6144 + so, &As[buf][c * 8]);                  \
            GLOAD16(qhi + (size_t)(i0 + row) * 6144 + so, &Bs[buf][c * 8]);                  \
        }                                                                                    \
    }

    STAGE(0, kbase);
    int cur = 0;
    for (int s = 0; s < 6; ++s) {
        __syncthreads();
        if (s + 1 < 6) STAGE(cur ^ 1, kbase + (s + 1) * 64);
        #pragma unroll
        for (int kh = 0; kh < 2; ++kh) {
            bf16x8 a[4], b[4];
            #pragma unroll
            for (int mi = 0; mi < 4; ++mi) {
                int row = wr * 64 + mi * 16 + (lane & 15);
                int slot = (kh * 4 + (lane >> 4)) ^ (row & 7);
                a[mi] = *(const bf16x8*)&As[cur][row * 64 + slot * 8];
            }
            #pragma unroll
            for (int ni = 0; ni < 4; ++ni) {
                int row = wc * 64 + ni * 16 + (lane & 15);
                int slot = (kh * 4 + (lane >> 4)) ^ (row & 7);
                b[ni] = *(const bf16x8*)&Bs[cur][row * 64 + slot * 8];
            }
            #pragma unroll
            for (int mi = 0; mi < 4; ++mi)
                #pragma unroll
                for (int ni = 0; ni < 4; ++ni)
                    acc[mi][ni] = __builtin_amdgcn_mfma_f32_16x16x32_bf16(a[mi], b[ni], acc[mi][ni], 0, 0, 0);
        }
        cur ^= 1;
    }
    #undef STAGE

    int r4 = (lane >> 4) * 4, cn = lane & 15;
    #pragma unroll
    for (int mi = 0; mi < 4; ++mi)
        #pragma unroll
        for (int ni = 0; ni < 4; ++ni) {
            int i = i0 + wc * 64 + ni * 16 + cn;
            int nb = n0 + wr * 64 + mi * 16 + r4;
            ushort4v u;
            #pragma unroll
            for (int r = 0; r < 4; ++r) u[r] = bf16bits(acc[mi][ni][r]);
            *(ushort4v*)(Hout + (size_t)i * 2048 + nb) = u;
        }
}

// ---------------------------------------------------------------- K4: z-reduce + score + softmax (+ bf16 att)
__global__ __launch_bounds__(256) void score_softmax_kernel(
    const ushort_t* __restrict__ hpart, const float* __restrict__ b1g,
    const float* __restrict__ w2g, const float* __restrict__ b2g,
    float* __restrict__ att, ushort_t* __restrict__ attbf)
{
    int i = blockIdx.x, j = threadIdx.x;
    float hm[8];
    #pragma unroll
    for (int m = 0; m < 8; ++m) hm[m] = b1g[m];
    #pragma unroll 4
    for (int z = 0; z < 16; ++z) {
        ushort8 u = *(const ushort8*)(hpart + (size_t)z * 524288 + (size_t)i * 2048 + j * 8);
        #pragma unroll
        for (int m = 0; m < 8; ++m) hm[m] += bf2f(u[m]);
    }
    float sv = b2g[0];
    #pragma unroll
    for (int m = 0; m < 8; ++m) sv += fmaxf(hm[m], 0.f) * w2g[m];

    __shared__ float wred[4], wred2[4];
    float mx = sv;
    #pragma unroll
    for (int off = 32; off > 0; off >>= 1) mx = fmaxf(mx, __shfl_down(mx, off, 64));
    if ((j & 63) == 0) wred[j >> 6] = mx;
    __syncthreads();
    mx = fmaxf(fmaxf(wred[0], wred[1]), fmaxf(wred[2], wred[3]));

    float e = expf(sv - mx);
    float sum = e;
    #pragma unroll
    for (int off = 32; off > 0; off >>= 1) sum += __shfl_down(sum, off, 64);
    if ((j & 63) == 0) wred2[j >> 6] = sum;
    __syncthreads();
    sum = wred2[0] + wred2[1] + wred2[2] + wred2[3];

    float pv = e / sum;
    att[(size_t)i * 256 + j] = pv;
    attbf[(size_t)i * 256 + j] = bf16bits(pv);
}

// ---------------------------------------------------------------- K5: b = att @ v (A=vt(c), B=attbf(i)), 64x64 tiles, grid (96,4)
__global__ __launch_bounds__(256) void av_kernel(
    const ushort_t* __restrict__ attbf, const ushort_t* __restrict__ vt,
    float* __restrict__ bmat)
{
    __shared__ ushort_t As[2][64 * 64];   // vt rows (c)
    __shared__ ushort_t Bs[2][64 * 64];   // attbf rows (i)

    int tid = threadIdx.x, lane = tid & 63, wid = tid >> 6;
    int wr = wid >> 1, wc = wid & 1;
    int c0 = blockIdx.x * 64, i0 = blockIdx.y * 64;

    f32x4 acc[2][2] = {};

    #define STAGEAV(buf, koff)                                                              \
    {                                                                                       \
        _Pragma("unroll")                                                                   \
        for (int r = 0; r < 2; ++r) {                                                       \
            int c = r * 256 + tid; int row = c >> 3, slot = c & 7;                          \
            int so = (koff) + ((slot ^ (row & 7)) * 8);                                     \
            GLOAD16(vt + (size_t)(c0 + row) * 256 + so, &As[buf][c * 8]);                   \
            GLOAD16(attbf + (size_t)(i0 + row) * 256 + so, &Bs[buf][c * 8]);                \
        }                                                                                   \
    }

    int cur = 0;
    STAGEAV(0, 0);
    for (int s = 0; s < 4; ++s) {
        __syncthreads();
        if (s < 3) STAGEAV(cur ^ 1, (s + 1) * 64);
        #pragma unroll
        for (int kh = 0; kh < 2; ++kh) {
            bf16x8 a[2], b[2];
            #pragma unroll
            for (int mi = 0; mi < 2; ++mi) {
                int row = wr * 32 + mi * 16 + (lane & 15);
                int slot = (kh * 4 + (lane >> 4)) ^ (row & 7);
                a[mi] = *(const bf16x8*)&As[cur][row * 64 + slot * 8];
            }
            #pragma unroll
            for (int ni = 0; ni < 2; ++ni) {
                int row = wc * 32 + ni * 16 + (lane & 15);
                int slot = (kh * 4 + (lane >> 4)) ^ (row & 7);
                b[ni] = *(const bf16x8*)&Bs[cur][row * 64 + slot * 8];
            }
            #pragma unroll
            for (int mi = 0; mi < 2; ++mi)
                #pragma unroll
                for (int ni = 0; ni < 2; ++ni)
                    acc[mi][ni] = __builtin_amdgcn_mfma_f32_16x16x32_bf16(a[mi], b[ni], acc[mi][ni], 0, 0, 0);
        }
        cur ^= 1;
    }
    #undef STAGEAV

    // acc rows = c (4 consecutive at r4), col = i
    int r4 = (lane >> 4) * 4, cn = lane & 15;
    #pragma unroll
    for (int mi = 0; mi < 2; ++mi)
        #pragma unroll
        for (int ni = 0; ni < 2; ++ni) {
            int i = i0 + wc * 32 + ni * 16 + cn;
            int c = c0 + wr * 32 + mi * 16 + r4;
            int kk = c / 768, rem = c - kk * 768;
            int t = rem >> 6, d = rem & 63;
            float4 val;
            val.x = acc[mi][ni][0]; val.y = acc[mi][ni][1];
            val.z = acc[mi][ni][2]; val.w = acc[mi][ni][3];
            *(float4*)(bmat + ((size_t)i * 12 + t) * 512 + kk * 64 + d) = val;
        }
}

// ---------------------------------------------------------------- K6: y = relu(b@w3T+b3)@w4T+b4  (8 rows/block, grid 384)
__global__ __launch_bounds__(256) void out_kernel(
    const float* __restrict__ bmat, const float* __restrict__ w3t, const float* __restrict__ b3,
    const float* __restrict__ w4t, const float* __restrict__ b4, float* __restrict__ yout)
{
    int rb = blockIdx.x * 8;      // rows (i*12+t)
    int tid = threadIdx.x;
    __shared__ float rows[8 * 512];
    __shared__ float y1s[8 * 64];
    const float4* src = (const float4*)(bmat + (size_t)rb * 512);
    #pragma unroll
    for (int r = 0; r < 4; ++r) ((float4*)rows)[tid + r * 256] = src[tid + r * 256];
    __syncthreads();

    int dout = tid & 63, rg = tid >> 6;   // 4 row-groups x 2 rows
    float acc[2];
    float b3v = b3[dout];
    acc[0] = b3v; acc[1] = b3v;
    for (int c4 = 0; c4 < 128; ++c4) {
        float w0 = w3t[(c4 * 4 + 0) * 64 + dout];
        float w1v = w3t[(c4 * 4 + 1) * 64 + dout];
        float w2v = w3t[(c4 * 4 + 2) * 64 + dout];
        float w3v = w3t[(c4 * 4 + 3) * 64 + dout];
        #pragma unroll
        for (int jj = 0; jj < 2; ++jj) {
            float4 rv = *(const float4*)&rows[(rg * 2 + jj) * 512 + c4 * 4];
            acc[jj] += rv.x * w0 + rv.y * w1v + rv.z * w2v + rv.w * w3v;
        }
    }
    #pragma unroll
    for (int jj = 0; jj < 2; ++jj) y1s[(rg * 2 + jj) * 64 + dout] = fmaxf(acc[jj], 0.f);
    __syncthreads();

    int f = tid & 31, rh = tid >> 5;      // 8 rows, 1 per group
    float a2 = b4[f];
    #pragma unroll
    for (int dd = 0; dd < 64; ++dd) a2 += y1s[rh * 64 + dd] * w4t[dd * 32 + f];
    yout[(size_t)(rb + rh) * 32 + f] = a2;
}

// ---------------------------------------------------------------- launch
extern "C" void kernel_launch(void* const* d_in, const int* in_sizes, int n_in,
                              void* d_out, int out_size, void* d_ws, size_t ws_size,
                              hipStream_t stream) {
    (void)in_sizes; (void)n_in; (void)out_size; (void)ws_size;
    const float* x  = (const float*)d_in[0];
    const float* Wq = (const float*)d_in[1];
    const float* Wk = (const float*)d_in[2];
    const float* Wv = (const float*)d_in[3];
    const float* bq = (const float*)d_in[4];
    const float* bk = (const float*)d_in[5];
    const float* bv = (const float*)d_in[6];
    const float* w1 = (const float*)d_in[7];
    const float* b1 = (const float*)d_in[8];
    const float* w2 = (const float*)d_in[9];
    const float* b2 = (const float*)d_in[10];
    const float* w3 = (const float*)d_in[11];
    const float* b3 = (const float*)d_in[12];
    const float* w4 = (const float*)d_in[13];
    const float* b4 = (const float*)d_in[14];

    float* ws = (float*)d_ws;
    ushort_t* hpart = (ushort_t*)ws;                     // 16z x 524288 ushorts = [0, 4194304) float-slots
    size_t    off   = 4194304;
    ushort_t* qhi   = (ushort_t*)(ws + off);             // 1,572,864 ushorts
    ushort_t* ghi   = (ushort_t*)(ws + off + 786432);    // 12,582,912 ushorts
    ushort_t* vbf   = (ushort_t*)(ws + off + 7077888);   // 1,572,864 ushorts
    ushort_t* vt    = (ushort_t*)(ws + off + 7864320);   // 1,572,864 ushorts
    ushort_t* attbf = (ushort_t*)(ws + off + 8650752);   // 65,536 ushorts
    float*    w3t   = ws + off + 8683520;                // 32,768
    float*    w4t   = ws + off + 8716288;                // 2,048
    ushort_t* kbf   = (ushort_t*)(ws + off + 8718336);   // 1,572,864 ushorts
    float*    bmat  = (float*)ghi;                       // reuse (ghi dead after hgemm)

    float* yout = (float*)d_out;              // 98304
    float* att  = (float*)d_out + 98304;      // 65536

    qkv_kernel<<<1536, 256, 0, stream>>>(x, Wq, Wk, Wv, bq, bk, bv, qhi, kbf, vbf);
    gbuild_kernel<<<2449, 256, 0, stream>>>(kbf, w1, vbf, w3, w4, ghi, vt, w3t, w4t);
    hgemm_kernel<<<512, 256, 0, stream>>>(qhi, ghi, hpart);
    score_softmax_kernel<<<256, 256, 0, stream>>>(hpart, b1, w2, b2, att, attbf);
    av_kernel<<<dim3(96, 4), 256, 0, stream>>>(attbf, vt, bmat);
    out_kernel<<<384, 256, 0, stream>>>(bmat, w3t, b3, w4t, b4, yout);
}

// Round 12
// 62.040 us; speedup vs baseline: 1.2850x; 1.2156x over previous
//
#include <hip/hip_runtime.h>
#include <hip/hip_bf16.h>

// N=256, T=12, F=32, T_dim=8, D=64;  c-index: c = kk*768 + t*64 + d  (size 6144)
typedef unsigned short ushort_t;
typedef __bf16 bf16x8 __attribute__((ext_vector_type(8)));
typedef float f32x4 __attribute__((ext_vector_type(4)));
typedef ushort_t ushort8 __attribute__((ext_vector_type(8)));
typedef ushort_t ushort4v __attribute__((ext_vector_type(4)));

#define GLOAD16(gp, lp) \
    __builtin_amdgcn_global_load_lds((const __attribute__((address_space(1))) void*)(gp), \
                                     (__attribute__((address_space(3))) void*)(lp), 16, 0, 0)

__device__ __forceinline__ ushort_t bf16bits(float x) {
    __hip_bfloat16 h = __float2bfloat16(x);
    return *(ushort_t*)&h;
}
__device__ __forceinline__ float bf2f(ushort_t u) {
    unsigned v = (unsigned)u << 16;
    float f;
    __builtin_memcpy(&f, &v, 4);
    return f;
}

// ---------------------------------------------------------------- K1: QKV projection — streaming, one wave per (b, mat)
__global__ __launch_bounds__(256) void qkv_kernel(
    const float* __restrict__ x,
    const float* __restrict__ Wq, const float* __restrict__ Wk, const float* __restrict__ Wv,
    const float* __restrict__ bq, const float* __restrict__ bk, const float* __restrict__ bv,
    ushort_t* __restrict__ qhi, ushort_t* __restrict__ kbf, ushort_t* __restrict__ vbf)
{
    __shared__ float xs[4][12 * 36];       // per-wave x row, t-stride 36
    int tid = threadIdx.x;
    int wid = tid >> 6, l = tid & 63;
    int gid = blockIdx.x * 4 + wid;        // 0..6143, mat-major
    int mat = gid >> 11, b = gid & 2047;
    int j = b >> 3;

    const float* W    = (mat == 0) ? Wq : (mat == 1) ? Wk : Wv;
    const float* bias = (mat == 0) ? bq : (mat == 1) ? bk : bv;
    ushort_t*    out  = (mat == 0) ? qhi : (mat == 1) ? kbf : vbf;
    float scale = (mat == 0) ? 0.125f : 1.0f;

    {
        const float4* xsrc = (const float4*)(x + (size_t)j * 384);
        float4 g0 = xsrc[l];
        int flat0 = l * 4;
        float* dst0 = &xs[wid][(flat0 >> 5) * 36 + (flat0 & 31)];
        dst0[0] = g0.x; dst0[1] = g0.y; dst0[2] = g0.z; dst0[3] = g0.w;
        if (l < 32) {
            float4 g1 = xsrc[64 + l];
            int flat1 = 256 + l * 4;
            float* dst1 = &xs[wid][(flat1 >> 5) * 36 + (flat1 & 31)];
            dst1[0] = g1.x; dst1[1] = g1.y; dst1[2] = g1.z; dst1[3] = g1.w;
        }
    }
    __syncthreads();

    int dq = l & 15, tg = l >> 4;          // d-quad, t-group (t = tg*3 + i)
    const f32x4* w4 = (const f32x4*)(W + (size_t)b * 2048);
    f32x4 a0 = {0.f,0.f,0.f,0.f}, a1 = a0, a2 = a0;
    const float* xr = &xs[wid][tg * 3 * 36];
    #pragma unroll
    for (int f4 = 0; f4 < 8; ++f4) {
        f32x4 w0 = w4[(f4 * 4 + 0) * 16 + dq];
        f32x4 w1_ = w4[(f4 * 4 + 1) * 16 + dq];
        f32x4 w2_ = w4[(f4 * 4 + 2) * 16 + dq];
        f32x4 w3_ = w4[(f4 * 4 + 3) * 16 + dq];
        float4 xa = *(const float4*)&xr[0 * 36 + f4 * 4];
        float4 xb = *(const float4*)&xr[1 * 36 + f4 * 4];
        float4 xc = *(const float4*)&xr[2 * 36 + f4 * 4];
        a0 += w0 * xa.x + w1_ * xa.y + w2_ * xa.z + w3_ * xa.w;
        a1 += w0 * xb.x + w1_ * xb.y + w2_ * xb.z + w3_ * xb.w;
        a2 += w0 * xc.x + w1_ * xc.y + w2_ * xc.z + w3_ * xc.w;
    }

    f32x4 bv4 = *(const f32x4*)(bias + (size_t)b * 64 + dq * 4);
    size_t obase = (size_t)b * 768 + dq * 4;
    f32x4 r;
    ushort4v u;
    r = (a0 + bv4) * scale;
    u[0] = bf16bits(r[0]); u[1] = bf16bits(r[1]); u[2] = bf16bits(r[2]); u[3] = bf16bits(r[3]);
    *(ushort4v*)(out + obase + (size_t)(tg * 3 + 0) * 64) = u;
    r = (a1 + bv4) * scale;
    u[0] = bf16bits(r[0]); u[1] = bf16bits(r[1]); u[2] = bf16bits(r[2]); u[3] = bf16bits(r[3]);
    *(ushort4v*)(out + obase + (size_t)(tg * 3 + 1) * 64) = u;
    r = (a2 + bv4) * scale;
    u[0] = bf16bits(r[0]); u[1] = bf16bits(r[1]); u[2] = bf16bits(r[2]); u[3] = bf16bits(r[3]);
    *(ushort4v*)(out + obase + (size_t)(tg * 3 + 2) * 64) = u;
}

// ---------------------------------------------------------------- K2: H GEMM with in-kernel G-build (blocks 0..511) + prep tail (512..912)
// tile 64n x 256i, K=384 per z (BK=64, 6 steps); A = G (built in LDS from kbf/w1), B = qhi
// G[(j*8+m)][kk*768+t*64+d] = sum_s w1[m][kk*144+t*12+s] * kbf[(j*8+kk)][s*64+d]
__global__ __launch_bounds__(256, 2) void hgemm_kernel(
    const ushort_t* __restrict__ qhi, const ushort_t* __restrict__ kbf,
    const float* __restrict__ w1, ushort_t* __restrict__ hpart,
    const ushort_t* __restrict__ vbf, const float* __restrict__ w3, const float* __restrict__ w4,
    ushort_t* __restrict__ vt, float* __restrict__ w3t, float* __restrict__ w4t)
{
    __shared__ alignas(16) char sb[77056];
    int tid = threadIdx.x;
    int bid = blockIdx.x;                 // 0..912

    if (bid >= 512) {
        if (bid < 896) {
            // vbf [j][6144] -> vt[c][j]; 16 c-cols x 256 j per block
            ushort_t (*ts)[264] = (ushort_t(*)[264])sb;
            int c0 = (bid - 512) * 16;
            int cc = tid & 15, jg = tid >> 4;
            #pragma unroll 4
            for (int jj = 0; jj < 16; ++jj) {
                int jx = jg * 16 + jj;
                ts[cc][jx] = vbf[(size_t)jx * 6144 + c0 + cc];
            }
            __syncthreads();
            #pragma unroll
            for (int c = 0; c < 16; ++c)
                vt[(size_t)(c0 + c) * 256 + tid] = ts[c][tid];
            return;
        }
        if (bid < 912) {
            // w3 (64 dout x 512 c3, c3=d*8+kk) -> w3t[cb*64+dout], cb = kk*64+d
            int wb = bid - 896;
            #pragma unroll
            for (int r = 0; r < 8; ++r) {
                int e = wb * 2048 + r * 256 + tid;
                int dout = e >> 9, c3 = e & 511;
                int cb = ((c3 & 7) << 6) | (c3 >> 3);
                w3t[cb * 64 + dout] = w3[e];
            }
            return;
        }
        #pragma unroll
        for (int r = 0; r < 8; ++r) {
            int e = r * 256 + tid; int f = e >> 6, dd = e & 63;
            w4t[dd * 32 + f] = w4[e];
        }
        return;
    }

    ushort_t* Bs  = (ushort_t*)sb;             // [2][256*64] = 65536 B  (qhi, linear GLOAD16 dest)
    ushort_t* As  = (ushort_t*)(sb + 65536);   // [64*72]     =  9216 B  (G, padded stride 72)
    float*    w1s = (float*)(sb + 74752);      // [8*72]      =  2304 B

    int lane = tid & 63, wv = tid >> 6;
    int xcd = bid & 7, kq = bid >> 3;          // kq 0..63
    int z = xcd + 8 * (kq >> 5);               // 0..15
    int rem = kq & 31;                         // n-tile
    int n0 = rem * 64, jb = rem * 8;
    int kk = z >> 1, thalf = (z & 1) * 6;
    ushort_t* Hout = hpart + (size_t)z * 524288;

    // G-build thread decomposition
    int j_loc = tid >> 5, d8 = (tid >> 2) & 7, mg = tid & 3;

    // prologue: w1 slab (8 m x 72 consecutive floats) via async DMA
    if (tid < 144) {
        int m = tid / 18, r = tid % 18;
        GLOAD16(w1 + (size_t)m * 1152 + kk * 144 + thalf * 12 + r * 4, &w1s[m * 72 + r * 4]);
    }
    // k row slice to registers: 12 x ushort8 (fixed across steps)
    ushort8 kreg[12];
    {
        const ushort_t* kp = kbf + (size_t)((jb + j_loc) * 8 + kk) * 768 + d8 * 8;
        #pragma unroll
        for (int s = 0; s < 12; ++s) kreg[s] = *(const ushort8*)(kp + s * 64);
    }
    __syncthreads();   // w1s + kreg ready

    f32x4 acc[4][4] = {};

    #define GBUILD(st)                                                          \
    {                                                                           \
        float ag0[8] = {0.f,0.f,0.f,0.f,0.f,0.f,0.f,0.f};                       \
        float ag1[8] = {0.f,0.f,0.f,0.f,0.f,0.f,0.f,0.f};                       \
        _Pragma("unroll")                                                       \
        for (int s = 0; s < 12; ++s) {                                          \
            float kf[8];                                                        \
            _Pragma("unroll")                                                   \
            for (int dd = 0; dd < 8; ++dd) kf[dd] = bf2f(kreg[s][dd]);          \
            float wa = w1s[(mg * 2 + 0) * 72 + (st) * 12 + s];                  \
            float wb = w1s[(mg * 2 + 1) * 72 + (st) * 12 + s];                  \
            _Pragma("unroll")                                                   \
            for (int dd = 0; dd < 8; ++dd) {                                    \
                ag0[dd] += wa * kf[dd];                                         \
                ag1[dd] += wb * kf[dd];                                         \
            }                                                                   \
        }                                                                       \
        int row0 = j_loc * 8 + mg * 2;                                          \
        int sl0 = d8 ^ (row0 & 7), sl1 = d8 ^ ((row0 + 1) & 7);                 \
        ushort8 u0, u1;                                                         \
        _Pragma("unroll")                                                       \
        for (int dd = 0; dd < 8; ++dd) { u0[dd] = bf16bits(ag0[dd]); u1[dd] = bf16bits(ag1[dd]); } \
        *(ushort8*)&As[row0 * 72 + sl0 * 8] = u0;                               \
        *(ushort8*)&As[(row0 + 1) * 72 + sl1 * 8] = u1;                         \
    }

    #define STAGE_B(buf, st)                                                    \
    {                                                                           \
        int koff = kk * 768 + (thalf + (st)) * 64;                              \
        _Pragma("unroll")                                                       \
        for (int r = 0; r < 8; ++r) {                                           \
            int c = r * 256 + tid; int row = c >> 3, slot = c & 7;              \
            GLOAD16(qhi + (size_t)row * 6144 + koff + ((slot ^ (row & 7)) * 8), \
                    &Bs[(buf) * 16384 + c * 8]);                                \
        }                                                                       \
    }

    GBUILD(0);
    STAGE_B(0, 0);
    int cur = 0;
    for (int st = 0; st < 6; ++st) {
        __syncthreads();                       // As + Bs[cur] ready
        bf16x8 a[2][4], b[2][4];
        #pragma unroll
        for (int kh = 0; kh < 2; ++kh)
            #pragma unroll
            for (int mi = 0; mi < 4; ++mi) {
                int row = mi * 16 + (lane & 15);
                int slot = (kh * 4 + (lane >> 4)) ^ (row & 7);
                a[kh][mi] = *(const bf16x8*)&As[row * 72 + slot * 8];
            }
        #pragma unroll
        for (int kh = 0; kh < 2; ++kh)
            #pragma unroll
            for (int ni = 0; ni < 4; ++ni) {
                int row = wv * 64 + ni * 16 + (lane & 15);
                int slot = (kh * 4 + (lane >> 4)) ^ (row & 7);
                b[kh][ni] = *(const bf16x8*)&Bs[cur * 16384 + row * 64 + slot * 8];
            }
        __syncthreads();                       // frag reads done; As may be overwritten
        if (st + 1 < 6) { GBUILD(st + 1); STAGE_B(cur ^ 1, st + 1); }
        #pragma unroll
        for (int kh = 0; kh < 2; ++kh)
            #pragma unroll
            for (int mi = 0; mi < 4; ++mi)
                #pragma unroll
                for (int ni = 0; ni < 4; ++ni)
                    acc[mi][ni] = __builtin_amdgcn_mfma_f32_16x16x32_bf16(a[kh][mi], b[kh][ni], acc[mi][ni], 0, 0, 0);
        cur ^= 1;
    }
    #undef GBUILD
    #undef STAGE_B

    // acc rows = n (4 consecutive), col = i
    int r4 = (lane >> 4) * 4, cn = lane & 15;
    #pragma unroll
    for (int mi = 0; mi < 4; ++mi)
        #pragma unroll
        for (int ni = 0; ni < 4; ++ni) {
            int i = wv * 64 + ni * 16 + cn;
            int nb = n0 + mi * 16 + r4;
            ushort4v u;
            #pragma unroll
            for (int r = 0; r < 4; ++r) u[r] = bf16bits(acc[mi][ni][r]);
            *(ushort4v*)(Hout + (size_t)i * 2048 + nb) = u;
        }
}

// ---------------------------------------------------------------- K3: z-reduce + score + softmax (+ bf16 att)
__global__ __launch_bounds__(256) void score_softmax_kernel(
    const ushort_t* __restrict__ hpart, const float* __restrict__ b1g,
    const float* __restrict__ w2g, const float* __restrict__ b2g,
    float* __restrict__ att, ushort_t* __restrict__ attbf)
{
    int i = blockIdx.x, j = threadIdx.x;
    float hm[8];
    #pragma unroll
    for (int m = 0; m < 8; ++m) hm[m] = b1g[m];
    #pragma unroll 4
    for (int z = 0; z < 16; ++z) {
        ushort8 u = *(const ushort8*)(hpart + (size_t)z * 524288 + (size_t)i * 2048 + j * 8);
        #pragma unroll
        for (int m = 0; m < 8; ++m) hm[m] += bf2f(u[m]);
    }
    float sv = b2g[0];
    #pragma unroll
    for (int m = 0; m < 8; ++m) sv += fmaxf(hm[m], 0.f) * w2g[m];

    __shared__ float wred[4], wred2[4];
    float mx = sv;
    #pragma unroll
    for (int off = 32; off > 0; off >>= 1) mx = fmaxf(mx, __shfl_down(mx, off, 64));
    if ((j & 63) == 0) wred[j >> 6] = mx;
    __syncthreads();
    mx = fmaxf(fmaxf(wred[0], wred[1]), fmaxf(wred[2], wred[3]));

    float e = expf(sv - mx);
    float sum = e;
    #pragma unroll
    for (int off = 32; off > 0; off >>= 1) sum += __shfl_down(sum, off, 64);
    if ((j & 63) == 0) wred2[j >> 6] = sum;
    __syncthreads();
    sum = wred2[0] + wred2[1] + wred2[2] + wred2[3];

    float pv = e / sum;
    att[(size_t)i * 256 + j] = pv;
    attbf[(size_t)i * 256 + j] = bf16bits(pv);
}

// ---------------------------------------------------------------- K4: b = att @ v (A=vt(c), B=attbf(i)), 64x64 tiles, grid (96,4)
__global__ __launch_bounds__(256) void av_kernel(
    const ushort_t* __restrict__ attbf, const ushort_t* __restrict__ vt,
    float* __restrict__ bmat)
{
    __shared__ ushort_t As[2][64 * 64];   // vt rows (c)
    __shared__ ushort_t Bs[2][64 * 64];   // attbf rows (i)

    int tid = threadIdx.x, lane = tid & 63, wid = tid >> 6;
    int wr = wid >> 1, wc = wid & 1;
    int c0 = blockIdx.x * 64, i0 = blockIdx.y * 64;

    f32x4 acc[2][2] = {};

    #define STAGEAV(buf, koff)                                                              \
    {                                                                                       \
        _Pragma("unroll")                                                                   \
        for (int r = 0; r < 2; ++r) {                                                       \
            int c = r * 256 + tid; int row = c >> 3, slot = c & 7;                          \
            int so = (koff) + ((slot ^ (row & 7)) * 8);                                     \
            GLOAD16(vt + (size_t)(c0 + row) * 256 + so, &As[buf][c * 8]);                   \
            GLOAD16(attbf + (size_t)(i0 + row) * 256 + so, &Bs[buf][c * 8]);                \
        }                                                                                   \
    }

    int cur = 0;
    STAGEAV(0, 0);
    for (int s = 0; s < 4; ++s) {
        __syncthreads();
        if (s < 3) STAGEAV(cur ^ 1, (s + 1) * 64);
        #pragma unroll
        for (int kh = 0; kh < 2; ++kh) {
            bf16x8 a[2], b[2];
            #pragma unroll
            for (int mi = 0; mi < 2; ++mi) {
                int row = wr * 32 + mi * 16 + (lane & 15);
                int slot = (kh * 4 + (lane >> 4)) ^ (row & 7);
                a[mi] = *(const bf16x8*)&As[cur][row * 64 + slot * 8];
            }
            #pragma unroll
            for (int ni = 0; ni < 2; ++ni) {
                int row = wc * 32 + ni * 16 + (lane & 15);
                int slot = (kh * 4 + (lane >> 4)) ^ (row & 7);
                b[ni] = *(const bf16x8*)&Bs[cur][row * 64 + slot * 8];
            }
            #pragma unroll
            for (int mi = 0; mi < 2; ++mi)
                #pragma unroll
                for (int ni = 0; ni < 2; ++ni)
                    acc[mi][ni] = __builtin_amdgcn_mfma_f32_16x16x32_bf16(a[mi], b[ni], acc[mi][ni], 0, 0, 0);
        }
        cur ^= 1;
    }
    #undef STAGEAV

    int r4 = (lane >> 4) * 4, cn = lane & 15;
    #pragma unroll
    for (int mi = 0; mi < 2; ++mi)
        #pragma unroll
        for (int ni = 0; ni < 2; ++ni) {
            int i = i0 + wc * 32 + ni * 16 + cn;
            int c = c0 + wr * 32 + mi * 16 + r4;
            int kk = c / 768, rem = c - kk * 768;
            int t = rem >> 6, d = rem & 63;
            float4 val;
            val.x = acc[mi][ni][0]; val.y = acc[mi][ni][1];
            val.z = acc[mi][ni][2]; val.w = acc[mi][ni][3];
            *(float4*)(bmat + ((size_t)i * 12 + t) * 512 + kk * 64 + d) = val;
        }
}

// ---------------------------------------------------------------- K5: y = relu(b@w3T+b3)@w4T+b4  (8 rows/block, grid 384)
__global__ __launch_bounds__(256) void out_kernel(
    const float* __restrict__ bmat, const float* __restrict__ w3t, const float* __restrict__ b3,
    const float* __restrict__ w4t, const float* __restrict__ b4, float* __restrict__ yout)
{
    int rb = blockIdx.x * 8;      // rows (i*12+t)
    int tid = threadIdx.x;
    __shared__ float rows[8 * 512];
    __shared__ float y1s[8 * 64];
    const float4* src = (const float4*)(bmat + (size_t)rb * 512);
    #pragma unroll
    for (int r = 0; r < 4; ++r) ((float4*)rows)[tid + r * 256] = src[tid + r * 256];
    __syncthreads();

    int dout = tid & 63, rg = tid >> 6;   // 4 row-groups x 2 rows
    float acc[2];
    float b3v = b3[dout];
    acc[0] = b3v; acc[1] = b3v;
    for (int c4 = 0; c4 < 128; ++c4) {
        float w0 = w3t[(c4 * 4 + 0) * 64 + dout];
        float w1v = w3t[(c4 * 4 + 1) * 64 + dout];
        float w2v = w3t[(c4 * 4 + 2) * 64 + dout];
        float w3v = w3t[(c4 * 4 + 3) * 64 + dout];
        #pragma unroll
        for (int jj = 0; jj < 2; ++jj) {
            float4 rv = *(const float4*)&rows[(rg * 2 + jj) * 512 + c4 * 4];
            acc[jj] += rv.x * w0 + rv.y * w1v + rv.z * w2v + rv.w * w3v;
        }
    }
    #pragma unroll
    for (int jj = 0; jj < 2; ++jj) y1s[(rg * 2 + jj) * 64 + dout] = fmaxf(acc[jj], 0.f);
    __syncthreads();

    int f = tid & 31, rh = tid >> 5;      // 8 rows, 1 per group
    float a2 = b4[f];
    #pragma unroll
    for (int dd = 0; dd < 64; ++dd) a2 += y1s[rh * 64 + dd] * w4t[dd * 32 + f];
    yout[(size_t)(rb + rh) * 32 + f] = a2;
}

// ---------------------------------------------------------------- launch
extern "C" void kernel_launch(void* const* d_in, const int* in_sizes, int n_in,
                              void* d_out, int out_size, void* d_ws, size_t ws_size,
                              hipStream_t stream) {
    (void)in_sizes; (void)n_in; (void)out_size; (void)ws_size;
    const float* x  = (const float*)d_in[0];
    const float* Wq = (const float*)d_in[1];
    const float* Wk = (const float*)d_in[2];
    const float* Wv = (const float*)d_in[3];
    const float* bq = (const float*)d_in[4];
    const float* bk = (const float*)d_in[5];
    const float* bv = (const float*)d_in[6];
    const float* w1 = (const float*)d_in[7];
    const float* b1 = (const float*)d_in[8];
    const float* w2 = (const float*)d_in[9];
    const float* b2 = (const float*)d_in[10];
    const float* w3 = (const float*)d_in[11];
    const float* b3 = (const float*)d_in[12];
    const float* w4 = (const float*)d_in[13];
    const float* b4 = (const float*)d_in[14];

    float* ws = (float*)d_ws;
    ushort_t* hpart = (ushort_t*)ws;                     // 16z x 524288 ushorts = [0, 4194304) float-slots
    size_t    off   = 4194304;
    ushort_t* qhi   = (ushort_t*)(ws + off);             // 1,572,864 ushorts
    ushort_t* kbf   = (ushort_t*)(ws + off + 786432);
    ushort_t* vbf   = (ushort_t*)(ws + off + 1572864);
    ushort_t* vt    = (ushort_t*)(ws + off + 2359296);
    ushort_t* attbf = (ushort_t*)(ws + off + 3145728);   // 65,536 ushorts
    float*    w3t   = ws + off + 3178496;                // 32,768
    float*    w4t   = ws + off + 3211264;                // 2,048
    float*    bmat  = ws + off + 3213312;                // 1,572,864

    float* yout = (float*)d_out;              // 98304
    float* att  = (float*)d_out + 98304;      // 65536

    qkv_kernel<<<1536, 256, 0, stream>>>(x, Wq, Wk, Wv, bq, bk, bv, qhi, kbf, vbf);
    hgemm_kernel<<<913, 256, 0, stream>>>(qhi, kbf, w1, hpart, vbf, w3, w4, vt, w3t, w4t);
    score_softmax_kernel<<<256, 256, 0, stream>>>(hpart, b1, w2, b2, att, attbf);
    av_kernel<<<dim3(96, 4), 256, 0, stream>>>(attbf, vt, bmat);
    out_kernel<<<384, 256, 0, stream>>>(bmat, w3t, b3, w4t, b4, yout);
}